// Round 2
// baseline (140.151 us; speedup 1.0000x reference)
//
#include <hip/hip_runtime.h>

// NCC (local normalized cross-correlation) loss, 9x9x9 window, zero-pad.
// Volume: [1,1,128,160,192] f32. Output: scalar f32 = 1 - mean(cc).
//
// Separable box filter, 3 passes + fused cc/reduce in pass3.
// R2: sliding-window (running sum) along the sweep axis in pass2/pass3 —
//     2 LDS reads per voxel instead of 9 (or 45) — plus zeroed LDS halo
//     pads so the hot loops have no boundary branches.

#define D_ 128
#define H_ 160
#define W_ 192
#define HW_ (H_ * W_)
#define N_ (D_ * H_ * W_)          // 3,932,160
#define WIN_INV (1.0f / 729.0f)

// ---------------- pass1: W-axis box sum of 5 derived channels -------------
__global__ __launch_bounds__(192) void ncc_pass1(const float* __restrict__ I,
                                                 const float* __restrict__ J,
                                                 float* __restrict__ ws,
                                                 float* __restrict__ acc) {
    __shared__ float sI[W_];
    __shared__ float sJ[W_];
    const int line = blockIdx.x;            // d*H_ + h
    const int w = threadIdx.x;
    const int base = line * W_;
    sI[w] = I[base + w];
    sJ[w] = J[base + w];
    if (line == 0 && w == 0) *acc = 0.0f;   // zero reduction accumulator
    __syncthreads();
    float s1 = 0.f, s2 = 0.f, s3 = 0.f, s4 = 0.f, s5 = 0.f;
#pragma unroll
    for (int j = -4; j <= 4; ++j) {
        int idx = w + j;
        if (idx >= 0 && idx < W_) {
            float a = sI[idx], b = sJ[idx];
            s1 += a; s2 += b; s3 += a * a; s4 += b * b; s5 += a * b;
        }
    }
    ws[0 * N_ + base + w] = s1;
    ws[1 * N_ + base + w] = s2;
    ws[2 * N_ + base + w] = s3;
    ws[3 * N_ + base + w] = s4;
    ws[4 * N_ + base + w] = s5;
}

// ---------------- pass2: H-axis box sum, in place, sliding window ----------
// One block per (d, channel, 64-wide w-tile). LDS rows are h+5 (5 front pad,
// 4 back pad, all zeroed) so the sliding loop needs no bounds checks.
__global__ __launch_bounds__(256) void ncc_pass2(float* __restrict__ ws) {
    __shared__ float tile[H_ + 9][64];      // rows: pad 0..4 | h+5 | pad 165..168
    const int b = blockIdx.x;
    const int wt = b % (W_ / 64);
    const int c = (b / (W_ / 64)) % 5;
    const int d = b / ((W_ / 64) * 5);
    const int cbase = c * N_ + d * HW_ + wt * 64;

    // zero the 9 pad rows
    for (int i = threadIdx.x; i < 9 * 64; i += 256) {
        int r = i >> 6, w = i & 63;
        int row = (r < 5) ? r : (160 + r);  // 0..4 and 165..168
        tile[row][w] = 0.f;
    }
    // stage (coalesced 256B per wave)
    for (int i = threadIdx.x; i < H_ * 64; i += 256) {
        int h = i >> 6, w = i & 63;
        tile[h + 5][w] = ws[cbase + h * W_ + w];
    }
    __syncthreads();

    const int w = threadIdx.x & 63;
    const int r = threadIdx.x >> 6;         // 0..3, each owns 40 h's
    const int h0 = r * 40;
    float s = 0.f;
#pragma unroll
    for (int j = 0; j < 9; ++j) s += tile[h0 + 1 + j][w];   // taps h0-4..h0+4
    ws[cbase + h0 * W_ + w] = s;
    for (int h = h0 + 1; h < h0 + 40; ++h) {
        s += tile[h + 9][w] - tile[h][w];   // +(h+4), -(h-5)
        ws[cbase + h * W_ + w] = s;
    }
}

// -------- pass3: D-axis box sum + cc + global reduce, sliding window -------
// One block (128 threads) per (h, 16-wide w-tile). All 5 channels staged with
// zeroed d-pads; each thread owns a 16-long d-run per (w) column.
__device__ __forceinline__ float ccf(const float S[5]) {
    float cross = S[4] - S[1] * S[0] * WIN_INV;
    float Ivar  = S[2] - S[0] * S[0] * WIN_INV;
    float Jvar  = S[3] - S[1] * S[1] * WIN_INV;
    return cross * cross / (Ivar * Jvar + 1e-5f);
}

__global__ __launch_bounds__(128) void ncc_pass3(const float* __restrict__ ws,
                                                 float* __restrict__ acc) {
    __shared__ float tile[5][D_ + 9][17];   // rows: pad 0..4 | d+5 | pad 133..136
    const int b = blockIdx.x;
    const int wt = b % (W_ / 16);
    const int h = b / (W_ / 16);
    const int base = h * W_ + wt * 16;

    // zero pad rows (5 ch x 9 rows x 17 cols = 765)
    for (int i = threadIdx.x; i < 5 * 9 * 17; i += 128) {
        int c = i / (9 * 17);
        int rr = (i / 17) % 9;
        int w = i % 17;
        int row = (rr < 5) ? rr : (128 + rr);   // 0..4 and 133..136
        tile[c][row][w] = 0.f;
    }
#pragma unroll
    for (int c = 0; c < 5; ++c) {
        for (int i = threadIdx.x; i < D_ * 16; i += 128) {
            int d = i >> 4, w = i & 15;
            tile[c][d + 5][w] = ws[c * N_ + base + d * HW_ + w];
        }
    }
    __syncthreads();

    const int w = threadIdx.x & 15;
    const int r = threadIdx.x >> 4;         // 0..7, each owns 16 d's
    const int d0 = r * 16;
    float S[5] = {0.f, 0.f, 0.f, 0.f, 0.f};
#pragma unroll
    for (int j = 0; j < 9; ++j) {
#pragma unroll
        for (int c = 0; c < 5; ++c) S[c] += tile[c][d0 + 1 + j][w];
    }
    float sum = ccf(S);
    for (int d = d0 + 1; d < d0 + 16; ++d) {
#pragma unroll
        for (int c = 0; c < 5; ++c) S[c] += tile[c][d + 9][w] - tile[c][d][w];
        sum += ccf(S);
    }

    // reduce: wave shuffle, then 2 partials via LDS
    for (int off = 32; off; off >>= 1) sum += __shfl_down(sum, off, 64);
    __shared__ float wsum[2];
    const int lane = threadIdx.x & 63, wv = threadIdx.x >> 6;
    if (lane == 0) wsum[wv] = sum;
    __syncthreads();
    if (threadIdx.x == 0) atomicAdd(acc, wsum[0] + wsum[1]);
}

__global__ void ncc_finalize(const float* __restrict__ acc,
                             float* __restrict__ out) {
    out[0] = 1.0f - acc[0] * (1.0f / (float)N_);
}

extern "C" void kernel_launch(void* const* d_in, const int* in_sizes, int n_in,
                              void* d_out, int out_size, void* d_ws, size_t ws_size,
                              hipStream_t stream) {
    const float* I = (const float*)d_in[0];   // y_true
    const float* J = (const float*)d_in[1];   // y_pred
    float* ws = (float*)d_ws;                  // 5 channels of N_ floats
    float* acc = ws + 5 * N_;                  // 1-float accumulator
    float* out = (float*)d_out;

    ncc_pass1<<<D_ * H_, 192, 0, stream>>>(I, J, ws, acc);
    ncc_pass2<<<D_ * 5 * (W_ / 64), 256, 0, stream>>>(ws);
    ncc_pass3<<<H_ * (W_ / 16), 128, 0, stream>>>(ws, acc);
    ncc_finalize<<<1, 1, 0, stream>>>(acc, out);
}

// Round 3
// 67.869 us; speedup vs baseline: 2.0650x; 2.0650x over previous
//
#include <hip/hip_runtime.h>

// NCC (local normalized cross-correlation) loss, 9x9x9 window, zero-pad.
// Volume: [1,1,128,160,192] f32. Output: scalar f32 = 1 - mean(cc).
//
// Separable box filter:
//   pass1: W-axis sums of 5 derived channels (LDS line buffer).
//   pass2: H-axis sums, IN PLACE, register-FIFO streaming (no LDS).
//          Thread owns one (c,d,w) column; 1 coalesced read + 1 write /voxel.
//   pass3: D-axis sums + cc + global reduce, register-FIFO streaming.
//          Thread owns one (h,w) pixel for a 32-deep d-chunk; 5 reads/voxel.
//   finalize: out = 1 - acc/N.

#define D_ 128
#define H_ 160
#define W_ 192
#define HW_ (H_ * W_)
#define N_ (D_ * H_ * W_)          // 3,932,160
#define WIN_INV (1.0f / 729.0f)
#define CHUNK3 32                  // d-chunk length in pass3

// ---------------- pass1: W-axis box sum of 5 derived channels -------------
__global__ __launch_bounds__(192) void ncc_pass1(const float* __restrict__ I,
                                                 const float* __restrict__ J,
                                                 float* __restrict__ ws,
                                                 float* __restrict__ acc) {
    __shared__ float sI[W_];
    __shared__ float sJ[W_];
    const int line = blockIdx.x;            // d*H_ + h
    const int w = threadIdx.x;
    const int base = line * W_;
    sI[w] = I[base + w];
    sJ[w] = J[base + w];
    if (line == 0 && w == 0) *acc = 0.0f;   // zero reduction accumulator
    __syncthreads();
    float s1 = 0.f, s2 = 0.f, s3 = 0.f, s4 = 0.f, s5 = 0.f;
#pragma unroll
    for (int j = -4; j <= 4; ++j) {
        int idx = w + j;
        if (idx >= 0 && idx < W_) {
            float a = sI[idx], b = sJ[idx];
            s1 += a; s2 += b; s3 += a * a; s4 += b * b; s5 += a * b;
        }
    }
    ws[0 * N_ + base + w] = s1;
    ws[1 * N_ + base + w] = s2;
    ws[2 * N_ + base + w] = s3;
    ws[3 * N_ + base + w] = s4;
    ws[4 * N_ + base + w] = s5;
}

// -------- pass2: H-axis box sum, in place, register-FIFO streaming --------
// Thread t -> (c, d, w); walks h = 0..159. In-place safe: each thread touches
// only its own column, and the read of row i (lead tap at step i-5) always
// precedes the write of row i (at step i).
__global__ __launch_bounds__(256) void ncc_pass2(float* __restrict__ ws) {
    const int t = blockIdx.x * 256 + threadIdx.x;   // < 5*128*192 = 122880
    const int c = t / (D_ * W_);
    const int rem = t % (D_ * W_);
    const int d = rem / W_;
    const int w = rem % W_;
    float* col = ws + c * N_ + d * HW_ + w;

    float win[9];
    float S = 0.f;
#pragma unroll
    for (int j = 0; j < 9; ++j) {
        int hh = j - 4;
        float v = (hh >= 0) ? col[hh * W_] : 0.f;
        win[j] = v; S += v;
    }
#pragma unroll
    for (int h = 0; h < H_; ++h) {
        col[h * W_] = S;
        if (h + 1 < H_) {
            int hh = h + 5;
            float v = (hh < H_) ? col[hh * W_] : 0.f;
            S += v - win[0];
#pragma unroll
            for (int j = 0; j < 8; ++j) win[j] = win[j + 1];
            win[8] = v;
        }
    }
}

// ---- pass3: D-axis box sum + cc + reduce, register-FIFO streaming --------
// Thread -> pixel p = h*W_+w (lane-contiguous => 256B coalesced loads),
// walks a CHUNK3-long d range with a 5ch x 9 register FIFO.
__global__ __launch_bounds__(256) void ncc_pass3(const float* __restrict__ ws,
                                                 float* __restrict__ acc) {
    const int p = (blockIdx.x % (HW_ / 256)) * 256 + threadIdx.x;
    const int d0 = (blockIdx.x / (HW_ / 256)) * CHUNK3;
    const float* base = ws + p;

    float win[5][9];
    float S[5];
    float sum = 0.f;
#pragma unroll
    for (int c = 0; c < 5; ++c) {
        S[c] = 0.f;
#pragma unroll
        for (int j = 0; j < 9; ++j) {
            int dd = d0 - 4 + j;
            float v = ((unsigned)dd < (unsigned)D_) ? base[c * N_ + dd * HW_] : 0.f;
            win[c][j] = v; S[c] += v;
        }
    }
#pragma unroll
    for (int i = 0; i < CHUNK3; ++i) {
        float cross = S[4] - S[1] * S[0] * WIN_INV;
        float Ivar  = S[2] - S[0] * S[0] * WIN_INV;
        float Jvar  = S[3] - S[1] * S[1] * WIN_INV;
        sum += cross * cross / (Ivar * Jvar + 1e-5f);
        if (i + 1 < CHUNK3) {
            int dd = d0 + i + 5;
            bool ok = dd < D_;                      // wave-uniform predicate
#pragma unroll
            for (int c = 0; c < 5; ++c) {
                float v = ok ? base[c * N_ + dd * HW_] : 0.f;
                S[c] += v - win[c][0];
#pragma unroll
                for (int j = 0; j < 8; ++j) win[c][j] = win[c][j + 1];
                win[c][8] = v;
            }
        }
    }

    // block reduce: wave shuffle, then 4 partials via LDS
    for (int off = 32; off; off >>= 1) sum += __shfl_down(sum, off, 64);
    __shared__ float wsum[4];
    const int lane = threadIdx.x & 63, wv = threadIdx.x >> 6;
    if (lane == 0) wsum[wv] = sum;
    __syncthreads();
    if (threadIdx.x == 0)
        atomicAdd(acc, wsum[0] + wsum[1] + wsum[2] + wsum[3]);
}

__global__ void ncc_finalize(const float* __restrict__ acc,
                             float* __restrict__ out) {
    out[0] = 1.0f - acc[0] * (1.0f / (float)N_);
}

extern "C" void kernel_launch(void* const* d_in, const int* in_sizes, int n_in,
                              void* d_out, int out_size, void* d_ws, size_t ws_size,
                              hipStream_t stream) {
    const float* I = (const float*)d_in[0];   // y_true
    const float* J = (const float*)d_in[1];   // y_pred
    float* ws = (float*)d_ws;                  // 5 channels of N_ floats
    float* acc = ws + 5 * N_;                  // 1-float accumulator
    float* out = (float*)d_out;

    ncc_pass1<<<D_ * H_, 192, 0, stream>>>(I, J, ws, acc);
    ncc_pass2<<<(5 * D_ * W_) / 256, 256, 0, stream>>>(ws);
    ncc_pass3<<<(HW_ / 256) * (D_ / CHUNK3), 256, 0, stream>>>(ws, acc);
    ncc_finalize<<<1, 1, 0, stream>>>(acc, out);
}